// Round 5
// baseline (430.135 us; speedup 1.0000x reference)
//
#include <hip/hip_runtime.h>

// RNN: h_t = tanh(x_t*W_ih^T + b_ih + h W_hh^T + b_hh), out = h_T W_fc^T + b_fc
// B=8192, T=784, I=1, H=30 (pad 32), C=10. fp32.
//
// R5: DPP allgather. R1-R4 routed the per-step h exchange through LDS; the
// LDS return path (128 B/cy/CU) is 1/4 the combined SIMD width -> measured
// 300us == LDS-pipe roofline (32 batches/CU x 4KB return per step = 1024
// cy/CU-step). This version keeps h in VGPRs distributed across a 16-lane
// DPP row (lane r holds h[r], h[16+r]; 4 batches per wave) and performs the
// 32-wide dot with 15 row_ror:k rotations (VALU-rate, no LDS, no barriers).
// Weights are gathered at init with the rotation permutation baked in:
//   ror:k => lane r sees h[(r-k)&15], so wa[k] = W[row][(r-k)&15], etc.

#define TT 784
#define HH 30
#define CC 10
#define TPB 16
#define NB 16      // batches per 256-thread block

template<int CTRL>
__device__ __forceinline__ float rotf(float v) {
    return __int_as_float(__builtin_amdgcn_mov_dpp(
        __float_as_int(v), CTRL, 0xf, 0xf, false));
}

__global__ __launch_bounds__(256, 2)
void rnn_scan_kernel(const float* __restrict__ x,
                     const float* __restrict__ W_ih,
                     const float* __restrict__ W_hh,
                     const float* __restrict__ b_ih,
                     const float* __restrict__ b_hh,
                     const float* __restrict__ W_fc,
                     const float* __restrict__ b_fc,
                     float* __restrict__ out) {
    __shared__ float hbuf[NB][34];     // epilogue only

    const int tid = threadIdx.x;
    const int bl  = tid >> 4;          // local batch 0..15 (4 per wave)
    const int r   = tid & 15;          // lane within DPP row
    const int b   = blockIdx.x * NB + bl;
    const int r2  = r + 16;            // second owned row (30,31 = pad)

    // --- init-time weight gather with rotation permutation baked in ---
    float wa[16], wb[16], wc[16], wd[16];
    const bool v2 = (r2 < HH);
#pragma unroll
    for (int k = 0; k < 16; ++k) {
        const int j = (r - k) & 15;    // column delivered by ror:k (j < 16 < HH)
        const int c = 16 + j;          // high column (pad if >= HH)
        wa[k] = W_hh[r * HH + j];
        wb[k] = (c < HH) ? W_hh[r * HH + c] : 0.0f;
        wc[k] = v2 ? W_hh[r2 * HH + j] : 0.0f;
        wd[k] = (v2 && c < HH) ? W_hh[r2 * HH + c] : 0.0f;
    }
    float bias0 = b_ih[r] + b_hh[r];
    float wih0  = W_ih[r];
    float bias1 = v2 ? (b_ih[r2] + b_hh[r2]) : 0.0f;
    float wih1  = v2 ? W_ih[r2] : 0.0f;

    // Pin gathered weights so they stay VGPR-resident across the loop.
    asm volatile("" : "+v"(wa[0]), "+v"(wa[1]), "+v"(wa[2]),  "+v"(wa[3]),
                      "+v"(wa[4]), "+v"(wa[5]), "+v"(wa[6]),  "+v"(wa[7]),
                      "+v"(wa[8]), "+v"(wa[9]), "+v"(wa[10]), "+v"(wa[11]),
                      "+v"(wa[12]),"+v"(wa[13]),"+v"(wa[14]), "+v"(wa[15]));
    asm volatile("" : "+v"(wb[0]), "+v"(wb[1]), "+v"(wb[2]),  "+v"(wb[3]),
                      "+v"(wb[4]), "+v"(wb[5]), "+v"(wb[6]),  "+v"(wb[7]),
                      "+v"(wb[8]), "+v"(wb[9]), "+v"(wb[10]), "+v"(wb[11]),
                      "+v"(wb[12]),"+v"(wb[13]),"+v"(wb[14]), "+v"(wb[15]));
    asm volatile("" : "+v"(wc[0]), "+v"(wc[1]), "+v"(wc[2]),  "+v"(wc[3]),
                      "+v"(wc[4]), "+v"(wc[5]), "+v"(wc[6]),  "+v"(wc[7]),
                      "+v"(wc[8]), "+v"(wc[9]), "+v"(wc[10]), "+v"(wc[11]),
                      "+v"(wc[12]),"+v"(wc[13]),"+v"(wc[14]), "+v"(wc[15]));
    asm volatile("" : "+v"(wd[0]), "+v"(wd[1]), "+v"(wd[2]),  "+v"(wd[3]),
                      "+v"(wd[4]), "+v"(wd[5]), "+v"(wd[6]),  "+v"(wd[7]),
                      "+v"(wd[8]), "+v"(wd[9]), "+v"(wd[10]), "+v"(wd[11]),
                      "+v"(wd[12]),"+v"(wd[13]),"+v"(wd[14]), "+v"(wd[15]));
    asm volatile("" : "+v"(bias0), "+v"(wih0), "+v"(bias1), "+v"(wih1));

    float h0 = 0.0f, h1 = 0.0f;        // h[r], h[16+r]

    const float* xb = x + (size_t)b * TT;
    float4 xq = *(const float4*)(xb);

#define KSTEP(k) {                                          \
        const float r0 = rotf<0x120 | (k)>(h0);             \
        const float r1 = rotf<0x120 | (k)>(h1);             \
        acc0 = __builtin_fmaf(wa[k], r0, acc0);             \
        acc0 = __builtin_fmaf(wb[k], r1, acc0);             \
        acc1 = __builtin_fmaf(wc[k], r0, acc1);             \
        acc1 = __builtin_fmaf(wd[k], r1, acc1); }

    for (int q = 0; q < TT / 4; ++q) {
        float4 nxt = (q + 1 < TT / 4) ? *(const float4*)(xb + (q + 1) * 4)
                                      : make_float4(0.f, 0.f, 0.f, 0.f);
#pragma unroll
        for (int u = 0; u < 4; ++u) {
            const float xt = (u == 0) ? xq.x : (u == 1) ? xq.y
                           : (u == 2) ? xq.z : xq.w;
            float acc0 = __builtin_fmaf(xt, wih0, bias0);
            float acc1 = __builtin_fmaf(xt, wih1, bias1);
            // k = 0: no rotation
            acc0 = __builtin_fmaf(wa[0], h0, acc0);
            acc0 = __builtin_fmaf(wb[0], h1, acc0);
            acc1 = __builtin_fmaf(wc[0], h0, acc1);
            acc1 = __builtin_fmaf(wd[0], h1, acc1);
            KSTEP(1)  KSTEP(2)  KSTEP(3)  KSTEP(4)  KSTEP(5)
            KSTEP(6)  KSTEP(7)  KSTEP(8)  KSTEP(9)  KSTEP(10)
            KSTEP(11) KSTEP(12) KSTEP(13) KSTEP(14) KSTEP(15)
            // tanh(a) = 1 - 2/(e^{2a}+1);  e^{2a} = 2^(a*2*log2 e)
            const float e0 = __builtin_exp2f(acc0 * 2.885390081777927f);
            const float e1 = __builtin_exp2f(acc1 * 2.885390081777927f);
            h0 = __builtin_fmaf(-2.0f, __builtin_amdgcn_rcpf(e0 + 1.0f), 1.0f);
            h1 = __builtin_fmaf(-2.0f, __builtin_amdgcn_rcpf(e1 + 1.0f), 1.0f);
        }
        xq = nxt;
    }
#undef KSTEP

    // --- FC head: park h in LDS (wave-local), 10 lanes per batch emit out ---
    hbuf[bl][r]      = h0;
    hbuf[bl][16 + r] = h1;             // rows 30,31 write 0 (unused anyway)
    __builtin_amdgcn_wave_barrier();
    if (r < CC) {
        float acc = b_fc[r];
#pragma unroll
        for (int j = 0; j < HH; ++j)
            acc = __builtin_fmaf(W_fc[r * HH + j], hbuf[bl][j], acc);
        out[(size_t)b * CC + r] = acc;
    }
}

extern "C" void kernel_launch(void* const* d_in, const int* in_sizes, int n_in,
                              void* d_out, int out_size, void* d_ws, size_t ws_size,
                              hipStream_t stream) {
    const float* x    = (const float*)d_in[0];
    const float* W_ih = (const float*)d_in[1];
    const float* W_hh = (const float*)d_in[2];
    const float* b_ih = (const float*)d_in[3];
    const float* b_hh = (const float*)d_in[4];
    const float* W_fc = (const float*)d_in[5];
    const float* b_fc = (const float*)d_in[6];

    hipLaunchKernelGGL(rnn_scan_kernel,
                       dim3(8192 / NB), dim3(NB * TPB), 0, stream,
                       x, W_ih, W_hh, b_ih, b_hh, W_fc, b_fc,
                       (float*)d_out);
}

// Round 6
// 429.833 us; speedup vs baseline: 1.0007x; 1.0007x over previous
//
#include <hip/hip_runtime.h>

// RNN: h_t = tanh(x_t*W_ih^T + b_ih + h W_hh^T + b_hh), out = h_T W_fc^T + b_fc
// B=8192, T=784, I=1, H=30 (pad 32), C=10. fp32.
//
// R6 = R5 (DPP allgather, zero LDS in the step loop) + amdgpu_waves_per_eu(2,2).
// R1-R5 post-mortems: the AMDGPU backend's occupancy heuristic targets 8
// waves/SIMD (<=64 VGPR) regardless of __launch_bounds__ *minimum*, and
// remats/spills any weight set bigger than ~16 regs (VGPR_Count came back
// 84/48/36/36/48). We only ever launch 2 waves/SIMD, so clamp the target with
// amdgpu_waves_per_eu(2,2) -> 256-VGPR budget -> the 64 gathered weight
// floats stay truly resident.
//
// Layout: lane r of a 16-lane DPP row holds h[r], h[16+r]; 4 batches/wave;
// the 32-wide dot = 15 row_ror:k rotations with init-time-permuted weights
// (ror:k delivers h[(r-k)&15] to lane r). Each rotf call has a SINGLE use so
// GCNDPPCombine can fold the mov_dpp into v_fmac_f32_dpp.

#define TT 784
#define HH 30
#define CC 10
#define TPB 16
#define NB 16      // batches per 256-thread block

template<int CTRL>
__device__ __forceinline__ float rotf(float v) {
    return __int_as_float(__builtin_amdgcn_mov_dpp(
        __float_as_int(v), CTRL, 0xf, 0xf, false));
}

__global__ __launch_bounds__(256)
__attribute__((amdgpu_waves_per_eu(2, 2)))
void rnn_scan_kernel(const float* __restrict__ x,
                     const float* __restrict__ W_ih,
                     const float* __restrict__ W_hh,
                     const float* __restrict__ b_ih,
                     const float* __restrict__ b_hh,
                     const float* __restrict__ W_fc,
                     const float* __restrict__ b_fc,
                     float* __restrict__ out) {
    __shared__ float hbuf[NB][34];     // epilogue only

    const int tid = threadIdx.x;
    const int bl  = tid >> 4;          // local batch 0..15 (4 per wave)
    const int r   = tid & 15;          // lane within DPP row
    const int b   = blockIdx.x * NB + bl;
    const int r2  = r + 16;            // second owned row (30,31 = pad)

    // --- init-time weight gather with rotation permutation baked in ---
    float wa[16], wb[16], wc[16], wd[16];
    const bool v2 = (r2 < HH);
#pragma unroll
    for (int k = 0; k < 16; ++k) {
        const int j = (r - k) & 15;    // column delivered by ror:k (j < 16 < HH)
        const int c = 16 + j;          // high column (pad if >= HH)
        wa[k] = W_hh[r * HH + j];
        wb[k] = (c < HH) ? W_hh[r * HH + c] : 0.0f;
        wc[k] = v2 ? W_hh[r2 * HH + j] : 0.0f;
        wd[k] = (v2 && c < HH) ? W_hh[r2 * HH + c] : 0.0f;
    }
    const float bias0 = b_ih[r] + b_hh[r];
    const float wih0  = W_ih[r];
    const float bias1 = v2 ? (b_ih[r2] + b_hh[r2]) : 0.0f;
    const float wih1  = v2 ? W_ih[r2] : 0.0f;

    float h0 = 0.0f, h1 = 0.0f;        // h[r], h[16+r]

    const float* xb = x + (size_t)b * TT;
    float4 xq = *(const float4*)(xb);

    // Each rotf call is single-use so the mov_dpp folds into v_fmac_f32_dpp.
#define KSTEP(k) {                                                   \
        acc0 = __builtin_fmaf(wa[k], rotf<0x120 | (k)>(h0), acc0);   \
        acc1 = __builtin_fmaf(wc[k], rotf<0x120 | (k)>(h0), acc1);   \
        acc0 = __builtin_fmaf(wb[k], rotf<0x120 | (k)>(h1), acc0);   \
        acc1 = __builtin_fmaf(wd[k], rotf<0x120 | (k)>(h1), acc1); }

    for (int q = 0; q < TT / 4; ++q) {
        float4 nxt = (q + 1 < TT / 4) ? *(const float4*)(xb + (q + 1) * 4)
                                      : make_float4(0.f, 0.f, 0.f, 0.f);
#pragma unroll
        for (int u = 0; u < 4; ++u) {
            const float xt = (u == 0) ? xq.x : (u == 1) ? xq.y
                           : (u == 2) ? xq.z : xq.w;
            float acc0 = __builtin_fmaf(xt, wih0, bias0);
            float acc1 = __builtin_fmaf(xt, wih1, bias1);
            // k = 0: no rotation
            acc0 = __builtin_fmaf(wa[0], h0, acc0);
            acc1 = __builtin_fmaf(wc[0], h0, acc1);
            acc0 = __builtin_fmaf(wb[0], h1, acc0);
            acc1 = __builtin_fmaf(wd[0], h1, acc1);
            KSTEP(1)  KSTEP(2)  KSTEP(3)  KSTEP(4)  KSTEP(5)
            KSTEP(6)  KSTEP(7)  KSTEP(8)  KSTEP(9)  KSTEP(10)
            KSTEP(11) KSTEP(12) KSTEP(13) KSTEP(14) KSTEP(15)
            // tanh(a) = 1 - 2/(e^{2a}+1);  e^{2a} = 2^(a*2*log2 e)
            const float e0 = __builtin_exp2f(acc0 * 2.885390081777927f);
            const float e1 = __builtin_exp2f(acc1 * 2.885390081777927f);
            h0 = __builtin_fmaf(-2.0f, __builtin_amdgcn_rcpf(e0 + 1.0f), 1.0f);
            h1 = __builtin_fmaf(-2.0f, __builtin_amdgcn_rcpf(e1 + 1.0f), 1.0f);
        }
        xq = nxt;
    }
#undef KSTEP

    // --- FC head: park h in LDS (wave-local), 10 lanes per batch emit out ---
    hbuf[bl][r]      = h0;
    hbuf[bl][16 + r] = h1;             // rows 30,31 hold 0-ish pad (unused)
    __builtin_amdgcn_wave_barrier();
    if (r < CC) {
        float acc = b_fc[r];
#pragma unroll
        for (int j = 0; j < HH; ++j)
            acc = __builtin_fmaf(W_fc[r * HH + j], hbuf[bl][j], acc);
        out[(size_t)b * CC + r] = acc;
    }
}

extern "C" void kernel_launch(void* const* d_in, const int* in_sizes, int n_in,
                              void* d_out, int out_size, void* d_ws, size_t ws_size,
                              hipStream_t stream) {
    const float* x    = (const float*)d_in[0];
    const float* W_ih = (const float*)d_in[1];
    const float* W_hh = (const float*)d_in[2];
    const float* b_ih = (const float*)d_in[3];
    const float* b_hh = (const float*)d_in[4];
    const float* W_fc = (const float*)d_in[5];
    const float* b_fc = (const float*)d_in[6];

    hipLaunchKernelGGL(rnn_scan_kernel,
                       dim3(8192 / NB), dim3(NB * TPB), 0, stream,
                       x, W_ih, W_hh, b_ih, b_hh, W_fc, b_fc,
                       (float*)d_out);
}

// Round 7
// 429.458 us; speedup vs baseline: 1.0016x; 1.0009x over previous
//
#include <hip/hip_runtime.h>

// RNN: h_t = tanh(x_t*W_ih^T + b_ih + h W_hh^T + b_hh), out = h_T W_fc^T + b_fc
// B=8192, T=784, I=1, H=30 (pad 32), C=10. fp32.
//
// R7: R5/R6 DPP structure, but the 64 per-lane weights are 64 INDIVIDUALLY
// NAMED scalar locals (no arrays). R1-R6 all showed FETCH_SIZE ~12.6 GB =
// ~2 KB per batch-step = per-step scratch reload of the weight slice: the
// weight ARRAYS were living in scratch (failed promotion and/or RA budget),
// and every step re-read them from HBM. Named scalars are plain SSA values;
// combined with amdgpu_waves_per_eu(2,2) (256-VGPR budget; we launch exactly
// 2 waves/SIMD) nothing is left to spill.
//
// Layout: lane r of a 16-lane DPP row holds h[r], h[16+r]; 4 batches/wave;
// 32-wide dot = 15 row_ror:k rotations, weights gathered at init with the
// rotation permutation baked in (ror:k delivers h[(r-k)&15] to lane r).

#define TT 784
#define HH 30
#define CC 10
#define TPB 16
#define NB 16      // batches per 256-thread block

template<int CTRL>
__device__ __forceinline__ float rotf(float v) {
    return __int_as_float(__builtin_amdgcn_mov_dpp(
        __float_as_int(v), CTRL, 0xf, 0xf, false));
}

__global__ __attribute__((amdgpu_flat_work_group_size(256, 256),
                          amdgpu_waves_per_eu(2, 2)))
void rnn_scan_kernel(const float* __restrict__ x,
                     const float* __restrict__ W_ih,
                     const float* __restrict__ W_hh,
                     const float* __restrict__ b_ih,
                     const float* __restrict__ b_hh,
                     const float* __restrict__ W_fc,
                     const float* __restrict__ b_fc,
                     float* __restrict__ out) {
    __shared__ float hbuf[NB][34];     // epilogue only

    const int tid = threadIdx.x;
    const int bl  = tid >> 4;          // local batch 0..15 (4 per wave)
    const int r   = tid & 15;          // lane within DPP row
    const int b   = blockIdx.x * NB + bl;
    const int r2  = r + 16;            // second owned row (30,31 = pad)
    const bool v2 = (r2 < HH);

    // --- 64 named weight scalars, rotation permutation baked in ---
#define GATHER(k)                                                          \
    const int  j##k = (r - (k)) & 15;                                      \
    const float wa##k = W_hh[r * HH + j##k];                               \
    const float wb##k = (16 + j##k < HH) ? W_hh[r * HH + 16 + j##k] : 0.f; \
    const float wc##k = v2 ? W_hh[r2 * HH + j##k] : 0.f;                   \
    const float wd##k = (v2 && 16 + j##k < HH) ? W_hh[r2 * HH + 16 + j##k] : 0.f;

    GATHER(0)  GATHER(1)  GATHER(2)  GATHER(3)
    GATHER(4)  GATHER(5)  GATHER(6)  GATHER(7)
    GATHER(8)  GATHER(9)  GATHER(10) GATHER(11)
    GATHER(12) GATHER(13) GATHER(14) GATHER(15)
#undef GATHER

    const float bias0 = b_ih[r] + b_hh[r];
    const float wih0  = W_ih[r];
    const float bias1 = v2 ? (b_ih[r2] + b_hh[r2]) : 0.0f;
    const float wih1  = v2 ? W_ih[r2] : 0.0f;

    float h0 = 0.0f, h1 = 0.0f;        // h[r], h[16+r]

    const float* xb = x + (size_t)b * TT;
    float4 xq = *(const float4*)(xb);

#define KSTEP(k) {                                                      \
        acc0 = __builtin_fmaf(wa##k, rotf<0x120 | (k)>(h0), acc0);      \
        acc1 = __builtin_fmaf(wc##k, rotf<0x120 | (k)>(h0), acc1);      \
        acc0 = __builtin_fmaf(wb##k, rotf<0x120 | (k)>(h1), acc0);      \
        acc1 = __builtin_fmaf(wd##k, rotf<0x120 | (k)>(h1), acc1); }

    for (int q = 0; q < TT / 4; ++q) {
        float4 nxt = (q + 1 < TT / 4) ? *(const float4*)(xb + (q + 1) * 4)
                                      : make_float4(0.f, 0.f, 0.f, 0.f);
#pragma unroll
        for (int u = 0; u < 4; ++u) {
            const float xt = (u == 0) ? xq.x : (u == 1) ? xq.y
                           : (u == 2) ? xq.z : xq.w;
            float acc0 = __builtin_fmaf(xt, wih0, bias0);
            float acc1 = __builtin_fmaf(xt, wih1, bias1);
            // k = 0: no rotation
            acc0 = __builtin_fmaf(wa0, h0, acc0);
            acc1 = __builtin_fmaf(wc0, h0, acc1);
            acc0 = __builtin_fmaf(wb0, h1, acc0);
            acc1 = __builtin_fmaf(wd0, h1, acc1);
            KSTEP(1)  KSTEP(2)  KSTEP(3)  KSTEP(4)  KSTEP(5)
            KSTEP(6)  KSTEP(7)  KSTEP(8)  KSTEP(9)  KSTEP(10)
            KSTEP(11) KSTEP(12) KSTEP(13) KSTEP(14) KSTEP(15)
            // tanh(a) = 1 - 2/(e^{2a}+1);  e^{2a} = 2^(a*2*log2 e)
            const float e0 = __builtin_exp2f(acc0 * 2.885390081777927f);
            const float e1 = __builtin_exp2f(acc1 * 2.885390081777927f);
            h0 = __builtin_fmaf(-2.0f, __builtin_amdgcn_rcpf(e0 + 1.0f), 1.0f);
            h1 = __builtin_fmaf(-2.0f, __builtin_amdgcn_rcpf(e1 + 1.0f), 1.0f);
        }
        xq = nxt;
    }
#undef KSTEP

    // --- FC head: park h in LDS (wave-local), 10 lanes per batch emit out ---
    hbuf[bl][r]      = h0;
    hbuf[bl][16 + r] = h1;             // rows 30,31 hold pad (unused)
    __builtin_amdgcn_wave_barrier();
    if (r < CC) {
        float acc = b_fc[r];
#pragma unroll
        for (int j = 0; j < HH; ++j)
            acc = __builtin_fmaf(W_fc[r * HH + j], hbuf[bl][j], acc);
        out[(size_t)b * CC + r] = acc;
    }
}

extern "C" void kernel_launch(void* const* d_in, const int* in_sizes, int n_in,
                              void* d_out, int out_size, void* d_ws, size_t ws_size,
                              hipStream_t stream) {
    const float* x    = (const float*)d_in[0];
    const float* W_ih = (const float*)d_in[1];
    const float* W_hh = (const float*)d_in[2];
    const float* b_ih = (const float*)d_in[3];
    const float* b_hh = (const float*)d_in[4];
    const float* W_fc = (const float*)d_in[5];
    const float* b_fc = (const float*)d_in[6];

    hipLaunchKernelGGL(rnn_scan_kernel,
                       dim3(8192 / NB), dim3(NB * TPB), 0, stream,
                       x, W_ih, W_hh, b_ih, b_hh, W_fc, b_fc,
                       (float*)d_out);
}